// Round 4
// baseline (266.152 us; speedup 1.0000x reference)
//
#include <hip/hip_runtime.h>
#include <hip/hip_bf16.h>

#define N_NODES 50000
#define N_EDGES 1000000
#define D_FEAT 512
#define F_ATTN 64
#define SLOPE 0.2f
#define CAP 64            // per-node list capacity; in-degree ~ Poisson(20), P(any node > 64) ~ 2e-10 (fixed seed, passed 3 rounds)
#define BINS 391          // 128 dst-nodes per bin; 391*128 = 50048 >= 50000
#define BINCAP 4096       // slots per bin; Poisson(2560) +30 sigma -> never
#define BINBLK 123        // ceil(1e6 / 8192) edge-binning blocks
#define WCVTBLK 64        // 65536 / 1024 W-convert role blocks
#define EPB 8192          // edges per bin block (16B-aligned int4 loads)

typedef __attribute__((ext_vector_type(8))) short short8;
typedef __attribute__((ext_vector_type(4))) float floatx4;

// fp32 -> bf16 (round-to-nearest-even), bit trick; inputs are finite randoms.
static __device__ __forceinline__ short f2bf(float x) {
    unsigned u = __float_as_uint(x);
    unsigned r = (u + 0x7FFFu + ((u >> 16) & 1u)) >> 16;
    return (short)r;
}

static __device__ __forceinline__ short8 cvt2(float4 x, float4 y) {
    short8 r;
    r[0] = f2bf(x.x); r[1] = f2bf(x.y); r[2] = f2bf(x.z); r[3] = f2bf(x.w);
    r[4] = f2bf(y.x); r[5] = f2bf(y.y); r[6] = f2bf(y.z); r[7] = f2bf(y.w);
    return r;
}

static __device__ __forceinline__ float bfu2f(unsigned short v) {
    return __uint_as_float((unsigned)v << 16);
}

// async global->LDS, 16B per lane. LDS dest = wave-uniform base + lane*16.
static __device__ __forceinline__ void g2lds16(const void* g, void* l) {
    __builtin_amdgcn_global_load_lds(
        (const __attribute__((address_space(1))) void*)g,
        (__attribute__((address_space(3))) void*)l, 16, 0, 0);
}

// ---------------- Fused coarse binning + W convert (independent roles).
// Bin role (blocks 0..122): per-edge rank from LDS atomic return; each
// (block,bin) claims ONE contiguous global segment with a single global
// atomic: 48K device atomics (~3 us) instead of 1M (~61 us fabric wall).
// Payload packs to 4B: (src << 7) | (dst & 127).
// Wcvt role (blocks 123..186): Wd,Wm fp32 -> Wb bf16 (65536 elems).
// gcount is zeroed by a prior hipMemsetAsync (cannot be zeroed in-launch:
// no ordering vs bin-role atomics).
__global__ __launch_bounds__(1024) void bin_kernel(
    const int* __restrict__ edge_src, const int* __restrict__ edge_dst,
    const float* __restrict__ Wd, const float* __restrict__ Wm,
    short* __restrict__ Wb,
    int* __restrict__ gcount, int* __restrict__ bins)
{
    __shared__ int hist[BINS];
    __shared__ int base[BINS];
    int tid = threadIdx.x;
    int bid = blockIdx.x;

    if (bid >= BINBLK) {
        // ---- W-convert role
        int i = (bid - BINBLK) * 1024 + tid;          // 0 .. 65535
        int half = F_ATTN * D_FEAT;                    // 32768
        float v = (i < half) ? Wd[i] : Wm[i - half];
        Wb[i] = f2bf(v);
        return;
    }

    if (tid < BINS) hist[tid] = 0;
    __syncthreads();

    int e0 = bid * EPB + tid * 8;          // per-thread 8 contiguous (int4 x2)
    int myV[8], myB[8], myR[8];
    if (e0 + 8 <= N_EDGES) {               // fast path: vector loads
        int4 d0 = *(const int4*)(edge_dst + e0);
        int4 d1 = *(const int4*)(edge_dst + e0 + 4);
        int4 s0 = *(const int4*)(edge_src + e0);
        int4 s1v = *(const int4*)(edge_src + e0 + 4);
        int dd[8] = {d0.x, d0.y, d0.z, d0.w, d1.x, d1.y, d1.z, d1.w};
        int ss[8] = {s0.x, s0.y, s0.z, s0.w, s1v.x, s1v.y, s1v.z, s1v.w};
        #pragma unroll
        for (int k = 0; k < 8; k++) {
            myV[k] = (ss[k] << 7) | (dd[k] & 127);
            myB[k] = dd[k] >> 7;
            myR[k] = atomicAdd(&hist[myB[k]], 1);
        }
    } else {                               // tail (last bin block only)
        #pragma unroll
        for (int k = 0; k < 8; k++) {
            int e = e0 + k;
            if (e < N_EDGES) {
                int d = edge_dst[e];
                int s = edge_src[e];
                myV[k] = (s << 7) | (d & 127);
                myB[k] = d >> 7;
                myR[k] = atomicAdd(&hist[myB[k]], 1);
            } else { myV[k] = -1; myB[k] = 0; myR[k] = 0; }
        }
    }
    __syncthreads();
    if (tid < BINS) {
        int c = hist[tid];
        base[tid] = c ? atomicAdd(&gcount[tid], c) : 0;
    }
    __syncthreads();
    #pragma unroll
    for (int k = 0; k < 8; k++) {
        if (myV[k] >= 0) {
            int pos = base[myB[k]] + myR[k];
            if (pos < BINCAP) bins[(myB[k] << 12) + pos] = myV[k];
        }
    }
}

// ---------------- Projection + fused attention scalars.
// A path is now DIRECT global->register (f32x8 per lane per ks, converted
// in-reg to bf16): the mfma_16x16x32 A-fragment is lane-private
// (row = lane&15, k = quad*8+[0..8)), and a wave's fragment load is 16 rows
// x 128 B contiguous -- no LDS staging needed. This halves LDS to 32 KB
// (B-only double buffer) -> 4 blocks/CU (16 waves/CU, was 8). A regs are
// double-buffered across the per-t-step barrier: the barrier's vmcnt(0)
// drain completes the prefetch for free.
__global__ __launch_bounds__(256, 4) void proj_kernel(
    const float* __restrict__ d_sim,
    const float* __restrict__ m_sim,
    const short* __restrict__ Wb,
    const float* __restrict__ Wa,
    const int* __restrict__ node_type,
    __hip_bfloat16* __restrict__ z,
    float* __restrict__ s1, float* __restrict__ s2)
{
    __shared__ char smem[32768];   // 2 bufs x 16KB B

    const int w      = threadIdx.x >> 6;
    const int lane   = threadIdx.x & 63;
    const int laneLo = lane & 15;
    const int quad   = lane >> 4;
    const int nodeBase = blockIdx.x * 64;

    // A: lane-private row pointer (row = nodeBase + w*16 + laneLo, clamped),
    // pre-offset by quad*8 (this lane's k-sub-chunk).
    int arow = nodeBase + w * 16 + laneLo; if (arow >= N_NODES) arow = N_NODES - 1;
    const float* rowPtr =
        ((node_type[arow] == 1) ? d_sim : m_sim) + (size_t)arow * D_FEAT + quad * 8;

    // B: instr i stages Wb rows (w*4+i)*8 .. +7; slot = lane&7,
    //    logical chunk = slot ^ (row&7)  (16B = 8 shorts)
    const short* bP[4];
    #pragma unroll
    for (int i = 0; i < 4; i++) {
        int r = (w * 4 + i) * 8 + (lane >> 3);
        int lc = (lane & 7) ^ (r & 7);
        bP[i] = Wb + (size_t)r * D_FEAT + (lc << 3);
    }

    floatx4 accD[4], accM[4];
    #pragma unroll
    for (int nt = 0; nt < 4; nt++) {
        accD[nt] = (floatx4){0.f, 0.f, 0.f, 0.f};
        accM[nt] = (floatx4){0.f, 0.f, 0.f, 0.f};
    }

    float4 aR[2][4];   // [buf][ks*2 + chunk]; static indexing via full unroll
    #pragma unroll
    for (int c = 0; c < 4; c++)
        aR[0][c] = *(const float4*)(rowPtr + ((c >> 1) * 32) + ((c & 1) * 4));
    {
        char* b0 = smem;
        #pragma unroll
        for (int i = 0; i < 4; i++)
            g2lds16(bP[i], b0 + (w * 4 + i) * 1024);
    }
    __syncthreads();   // drains vmcnt: B(0) in LDS, A(0) in regs

    const int rx = laneLo & 7;

    #pragma unroll
    for (int t = 0; t < 8; t++) {
        if (t < 7) {
            char* nb = smem + ((t + 1) & 1) * 16384;
            int k0 = (t + 1) * 64;
            #pragma unroll
            for (int i = 0; i < 4; i++)
                g2lds16(bP[i] + k0, nb + (w * 4 + i) * 1024);
            #pragma unroll
            for (int c = 0; c < 4; c++)
                aR[(t + 1) & 1][c] =
                    *(const float4*)(rowPtr + k0 + ((c >> 1) * 32) + ((c & 1) * 4));
        }
        const char* cb = smem + (t & 1) * 16384;
        #pragma unroll
        for (int ks = 0; ks < 2; ks++) {
            short8 a = cvt2(aR[t & 1][ks * 2], aR[t & 1][ks * 2 + 1]);
            int sl = ((ks * 4 + quad) ^ rx) << 4;
            #pragma unroll
            for (int nt = 0; nt < 4; nt++) {
                const char* rowD = cb + (nt * 16 + laneLo) * 128;
                short8 bD = *(const short8*)(rowD + sl);
                short8 bM = *(const short8*)(rowD + 64 * 128 + sl);
                accD[nt] = __builtin_amdgcn_mfma_f32_16x16x32_bf16(a, bD, accD[nt], 0, 0, 0);
                accM[nt] = __builtin_amdgcn_mfma_f32_16x16x32_bf16(a, bM, accM[nt], 0, 0, 0);
            }
        }
        __syncthreads();
    }

    float wa1[4], wa2[4];
    #pragma unroll
    for (int nt = 0; nt < 4; nt++) {
        wa1[nt] = Wa[nt * 16 + laneLo];
        wa2[nt] = Wa[F_ATTN + nt * 16 + laneLo];
    }

    // C/D layout: col = lane&15 (feature), row = quad*4 + reg (node)
    #pragma unroll
    for (int reg = 0; reg < 4; reg++) {
        int node = nodeBase + w * 16 + quad * 4 + reg;
        bool ok = node < N_NODES;
        int isD = ok ? (node_type[node] == 1) : 0;
        float p1 = 0.f, p2 = 0.f;
        #pragma unroll
        for (int nt = 0; nt < 4; nt++) {
            float v = isD ? accD[nt][reg] : accM[nt][reg];
            if (ok) z[(size_t)node * F_ATTN + nt * 16 + laneLo] = __float2bfloat16(v);
            p1 += v * wa1[nt];
            p2 += v * wa2[nt];
        }
        #pragma unroll
        for (int off = 8; off; off >>= 1) {
            p1 += __shfl_xor(p1, off);
            p2 += __shfl_xor(p2, off);
        }
        if (ok && laneLo == 0) { s1[node] = p1; s2[node] = p2; }
    }
}

// ---------------- Aggregation: one block per bin (128 nodes, 16 waves).
// Distribute bin edges to per-node LDS lists via LDS atomics, then wave w
// aggregates nodes w*8..w*8+7 with the 16-lane x 4-feature gather pattern.
// Gather loop now runs in 4-edge granules (was 16): avg cnt ~ 20 -> ~25%
// fewer wasted pad gathers. Weight recomputed: exp(leaky(s1[src]+s2[node]));
// softmax ratio identical without the max shift (logits O(1), no overflow).
__global__ __launch_bounds__(1024) void agg_kernel(
    const int* __restrict__ gcount, const int* __restrict__ bins,
    const float* __restrict__ s1, const float* __restrict__ s2,
    const __hip_bfloat16* __restrict__ z, float* __restrict__ out)
{
    __shared__ unsigned short list[128 * CAP];   // 16 KB
    __shared__ int lcnt[128];
    __shared__ float sW[16 * 64];                // 4 KB
    __shared__ int   sS[16 * 64];                // 4 KB
    int tid = threadIdx.x;
    int b   = blockIdx.x;
    if (tid < 128) lcnt[tid] = 0;
    __syncthreads();

    int bc = gcount[b]; if (bc > BINCAP) bc = BINCAP;
    for (int i = tid; i < bc; i += 1024) {
        int v = bins[(b << 12) + i];
        int n = v & 127;
        int s = v >> 7;
        int r = atomicAdd(&lcnt[n], 1);
        if (r < CAP) list[(n << 6) + r] = (unsigned short)s;
    }
    __syncthreads();

    int wv    = tid >> 6;            // 0..15
    int lane  = tid & 63;
    int fgrp  = (lane & 15) * 4;     // this lane's 4 features
    int ep    = lane >> 4;           // edge-slot offset 0..3
    int wbase = wv * 64;

    for (int j8 = 0; j8 < 8; j8++) {
        int ln   = wv * 8 + j8;                  // local node 0..127
        int node = (b << 7) + ln;
        bool nvalid = node < N_NODES;
        int cnt = nvalid ? lcnt[ln] : 0;
        if (cnt > CAP) cnt = CAP;                // overflow clamp

        int   src = 0;
        float wgt = 0.f;                         // pad slots keep w=0
        if (lane < cnt) {
            src = list[(ln << 6) + lane];
            float t = s1[src] + s2[node];
            float ev = (t > 0.f) ? t : SLOPE * t;
            wgt = __expf(ev);
        }
        float l = wgt;
        sW[wbase + lane] = wgt;                  // wave-private: no barrier
        sS[wbase + lane] = src;

        float4 h = {0.f, 0.f, 0.f, 0.f};
        int usteps = (cnt + 3) >> 2;             // 4-edge granules
        for (int uu = 0; uu < usteps; uu++) {    // pad slots (<=3) have w=0
            int slot = wbase + (uu << 2) + ep;
            float wj = sW[slot];
            int   sj = sS[slot];
            ushort4 zz = *(const ushort4*)((const unsigned short*)z +
                                           (size_t)sj * F_ATTN + fgrp);
            h.x += wj * bfu2f(zz.x);
            h.y += wj * bfu2f(zz.y);
            h.z += wj * bfu2f(zz.z);
            h.w += wj * bfu2f(zz.w);
        }
        // combine the 4 edge-slot groups (lanes differing in bits 4,5)
        #pragma unroll
        for (int off = 16; off <= 32; off <<= 1) {
            h.x += __shfl_xor(h.x, off);
            h.y += __shfl_xor(h.y, off);
            h.z += __shfl_xor(h.z, off);
            h.w += __shfl_xor(h.w, off);
        }
        #pragma unroll
        for (int off = 32; off; off >>= 1) l += __shfl_xor(l, off);

        if (ep == 0 && nvalid) {
            float inv = (cnt > 0) ? 1.f / l : 0.f;
            float4 o;
            float v;
            v = h.x * inv; o.x = (v > 0.f) ? v : (__expf(v) - 1.f);
            v = h.y * inv; o.y = (v > 0.f) ? v : (__expf(v) - 1.f);
            v = h.z * inv; o.z = (v > 0.f) ? v : (__expf(v) - 1.f);
            v = h.w * inv; o.w = (v > 0.f) ? v : (__expf(v) - 1.f);
            *(float4*)(out + (size_t)node * F_ATTN + fgrp) = o;
        }
    }
}

extern "C" void kernel_launch(void* const* d_in, const int* in_sizes, int n_in,
                              void* d_out, int out_size, void* d_ws, size_t ws_size,
                              hipStream_t stream) {
    const float* d_sim = (const float*)d_in[0];
    const float* m_sim = (const float*)d_in[1];
    const float* Wd    = (const float*)d_in[2];
    const float* Wm    = (const float*)d_in[3];
    const float* Wa    = (const float*)d_in[4];
    const int* node_type = (const int*)d_in[5];
    const int* edge_src  = (const int*)d_in[6];
    const int* edge_dst  = (const int*)d_in[7];
    float* out = (float*)d_out;

    char* ws = (char*)d_ws;
    // ws layout (bytes):
    __hip_bfloat16* z  = (__hip_bfloat16*)(ws + 0);        //  6,400,000
    float* s1          = (float*)(ws + 6400000);           //    200,000
    float* s2          = (float*)(ws + 6600000);           //    200,000
    int*   gcount      = (int*)  (ws + 6800000);           //      1,564
    short* Wb          = (short*)(ws + 7000000);           //    131,072 (16B aligned)
    int*   bins        = (int*)  (ws + 8388608);           //  6,406,144 (16KB-aligned bins)

    hipMemsetAsync(gcount, 0, BINS * sizeof(int), stream);
    bin_kernel<<<BINBLK + WCVTBLK, 1024, 0, stream>>>(
        edge_src, edge_dst, Wd, Wm, Wb, gcount, bins);
    proj_kernel<<<(N_NODES + 63) / 64, 256, 0, stream>>>(
        d_sim, m_sim, Wb, Wa, node_type, z, s1, s2);
    agg_kernel<<<BINS, 1024, 0, stream>>>(gcount, bins, s1, s2, z, out);
}

// Round 5
// 253.858 us; speedup vs baseline: 1.0484x; 1.0484x over previous
//
#include <hip/hip_runtime.h>
#include <hip/hip_bf16.h>

#define N_NODES 50000
#define N_EDGES 1000000
#define D_FEAT 512
#define F_ATTN 64
#define SLOPE 0.2f
#define CAP 64            // per-node list capacity; in-degree ~ Poisson(20), P(any node > 64) ~ 2e-10 (fixed seed, passed 4 rounds)
#define BINS 391          // 128 dst-nodes per bin; 391*128 = 50048 >= 50000
#define BINCAP 4096       // slots per bin; Poisson(2560) +30 sigma -> never
#define NPROJ 782         // ceil(N_NODES / 64) projection-role blocks
#define NBINBLK 489       // ceil(1e6 / 2048) bin-role blocks (256 thr x 8 edges)
#define EPB2 2048         // edges per bin-role block
#define NB_TOT (NPROJ + NBINBLK)

typedef __attribute__((ext_vector_type(8))) short short8;
typedef __attribute__((ext_vector_type(4))) float floatx4;

// fp32 -> bf16 (round-to-nearest-even), bit trick; inputs are finite randoms.
static __device__ __forceinline__ short f2bf(float x) {
    unsigned u = __float_as_uint(x);
    unsigned r = (u + 0x7FFFu + ((u >> 16) & 1u)) >> 16;
    return (short)r;
}

static __device__ __forceinline__ short8 cvt2(float4 x, float4 y) {
    short8 r;
    r[0] = f2bf(x.x); r[1] = f2bf(x.y); r[2] = f2bf(x.z); r[3] = f2bf(x.w);
    r[4] = f2bf(y.x); r[5] = f2bf(y.y); r[6] = f2bf(y.z); r[7] = f2bf(y.w);
    return r;
}

static __device__ __forceinline__ float bfu2f(unsigned short v) {
    return __uint_as_float((unsigned)v << 16);
}

// async global->LDS, 16B per lane. LDS dest = wave-uniform base + lane*16.
static __device__ __forceinline__ void g2lds16(const void* g, void* l) {
    __builtin_amdgcn_global_load_lds(
        (const __attribute__((address_space(1))) void*)g,
        (__attribute__((address_space(3))) void*)l, 16, 0, 0);
}

// ---------------- One-time W convert (Wd,Wm fp32 -> Wb bf16) + gcount zeroing.
// Must fully precede the fused kernel (proj role reads Wb, bin role atomics
// on gcount) -- separate dispatch gives that ordering.
__global__ __launch_bounds__(256) void wcvt_kernel(
    const float* __restrict__ Wd, const float* __restrict__ Wm,
    short* __restrict__ Wb, int* __restrict__ gcount)
{
    int i = blockIdx.x * 256 + threadIdx.x;           // 0 .. 65535
    int half = F_ATTN * D_FEAT;                        // 32768
    float v = (i < half) ? Wd[i] : Wm[i - half];
    Wb[i] = f2bf(v);
    if (i < BINS) gcount[i] = 0;
}

// ---------------- FUSED: edge-binning blocks interleaved 5:8 with projection
// blocks in one launch. The roles are fully independent (bin: edges->bins;
// proj: sim->z,s1,s2), so the ~12 us bin pass hides under proj's staging
// stalls instead of serializing. Unlike round-2's failed mega, the bin role
// here has no fabric-atomic wall (48K global atomics total) and tolerates
// 2-blocks/CU co-residency.
//
// Bin role: per-edge rank from LDS atomic return; each (block,bin) claims one
// contiguous global segment with a single global atomic. Payload packs to 4B:
// (src << 7) | (dst & 127).
// Proj role: the round-3-proven m97-style LDS GEMM (A and B staged via
// global_load_lds, XOR-swizzled chunks, dual D/M accumulators, fused
// s1/s2 = z . Wa reduction).
__global__ __launch_bounds__(256) void fused_kernel(
    const float* __restrict__ d_sim,
    const float* __restrict__ m_sim,
    const short* __restrict__ Wb,
    const float* __restrict__ Wa,
    const int* __restrict__ node_type,
    const int* __restrict__ edge_src,
    const int* __restrict__ edge_dst,
    __hip_bfloat16* __restrict__ z,
    float* __restrict__ s1, float* __restrict__ s2,
    int* __restrict__ gcount, int* __restrict__ bins)
{
    __shared__ char smem[65536];   // proj: 2 bufs x (16KB A + 16KB B); bin: hist/base

    const int bid = blockIdx.x;
    const int tid = threadIdx.x;
    // 5-in-13 interleave: 489/1271 ~ 5/13. nbBefore = designated-bin blocks
    // strictly before bid; designated blocks past bin 488 fall through to proj.
    const int r13 = bid % 13;
    const int nbBefore = (bid / 13) * 5 + (r13 < 5 ? r13 : 5);
    const bool isBin = (r13 < 5) && (nbBefore < NBINBLK);

    if (isBin) {
        // ---- bin role (256 threads, 2048 edges)
        int* hist = (int*)smem;            // BINS ints
        int* base = (int*)(smem + 4096);   // BINS ints
        const int q = nbBefore;
        for (int i = tid; i < BINS; i += 256) hist[i] = 0;
        __syncthreads();

        int e0 = q * EPB2 + tid * 8;       // per-thread 8 contiguous (int4 x2)
        int myV[8], myB[8], myR[8];
        if (e0 + 8 <= N_EDGES) {           // fast path: vector loads
            int4 d0 = *(const int4*)(edge_dst + e0);
            int4 d1 = *(const int4*)(edge_dst + e0 + 4);
            int4 s0 = *(const int4*)(edge_src + e0);
            int4 s1v = *(const int4*)(edge_src + e0 + 4);
            int dd[8] = {d0.x, d0.y, d0.z, d0.w, d1.x, d1.y, d1.z, d1.w};
            int ss[8] = {s0.x, s0.y, s0.z, s0.w, s1v.x, s1v.y, s1v.z, s1v.w};
            #pragma unroll
            for (int k = 0; k < 8; k++) {
                myV[k] = (ss[k] << 7) | (dd[k] & 127);
                myB[k] = dd[k] >> 7;
                myR[k] = atomicAdd(&hist[myB[k]], 1);
            }
        } else {                           // tail (last bin block only)
            #pragma unroll
            for (int k = 0; k < 8; k++) {
                int e = e0 + k;
                if (e < N_EDGES) {
                    int d = edge_dst[e];
                    int s = edge_src[e];
                    myV[k] = (s << 7) | (d & 127);
                    myB[k] = d >> 7;
                    myR[k] = atomicAdd(&hist[myB[k]], 1);
                } else { myV[k] = -1; myB[k] = 0; myR[k] = 0; }
            }
        }
        __syncthreads();
        for (int i = tid; i < BINS; i += 256) {
            int c = hist[i];
            base[i] = c ? atomicAdd(&gcount[i], c) : 0;
        }
        __syncthreads();
        #pragma unroll
        for (int k = 0; k < 8; k++) {
            if (myV[k] >= 0) {
                int pos = base[myB[k]] + myR[k];
                if (pos < BINCAP) bins[(myB[k] << 12) + pos] = myV[k];
            }
        }
        return;
    }

    // ---- projection role (round-3-proven structure, nodeBase from proj index)
    const int p      = bid - (nbBefore < NBINBLK ? nbBefore : NBINBLK);
    const int w      = tid >> 6;
    const int lane   = tid & 63;
    const int laneLo = lane & 15;
    const int quad   = lane >> 4;
    const int nodeBase = p * 64;

    // A: instr i stages tile rows w*16+i*4 .. +3; slot = lane&15,
    //    logical chunk = slot ^ (row&7)  (16B = 4 floats)
    const float* aP[4];
    #pragma unroll
    for (int i = 0; i < 4; i++) {
        int r = w * 16 + i * 4 + (lane >> 4);
        int arow = nodeBase + r; if (arow >= N_NODES) arow = N_NODES - 1;
        int lc = (lane & 15) ^ (r & 7);
        const float* src = (node_type[arow] == 1) ? d_sim : m_sim;
        aP[i] = src + (size_t)arow * D_FEAT + (lc << 2);
    }
    // B: instr i stages Wb rows (w*4+i)*8 .. +7; slot = lane&7,
    //    logical chunk = slot ^ (row&7)  (16B = 8 shorts)
    const short* bP[4];
    #pragma unroll
    for (int i = 0; i < 4; i++) {
        int r = (w * 4 + i) * 8 + (lane >> 3);
        int lc = (lane & 7) ^ (r & 7);
        bP[i] = Wb + (size_t)r * D_FEAT + (lc << 3);
    }

    floatx4 accD[4], accM[4];
    #pragma unroll
    for (int nt = 0; nt < 4; nt++) {
        accD[nt] = (floatx4){0.f, 0.f, 0.f, 0.f};
        accM[nt] = (floatx4){0.f, 0.f, 0.f, 0.f};
    }

    {
        char* b0 = smem;
        #pragma unroll
        for (int i = 0; i < 4; i++)
            g2lds16(aP[i], b0 + (w * 16 + i * 4) * 256);
        #pragma unroll
        for (int i = 0; i < 4; i++)
            g2lds16(bP[i], b0 + 16384 + (w * 4 + i) * 1024);
    }
    __syncthreads();

    const int rA  = w * 16 + laneLo;
    const int rx  = laneLo & 7;

    for (int t = 0; t < 8; t++) {
        if (t < 7) {
            char* nb = smem + ((t + 1) & 1) * 32768;
            int k0 = (t + 1) * 64;
            #pragma unroll
            for (int i = 0; i < 4; i++)
                g2lds16(aP[i] + k0, nb + (w * 16 + i * 4) * 256);
            #pragma unroll
            for (int i = 0; i < 4; i++)
                g2lds16(bP[i] + k0, nb + 16384 + (w * 4 + i) * 1024);
        }
        const char* cb = smem + (t & 1) * 32768;
        #pragma unroll
        for (int ks = 0; ks < 2; ks++) {
            int c0 = ks * 8 + quad * 2;
            float4 a0 = *(const float4*)(cb + rA * 256 + ((c0 ^ rx) << 4));
            float4 a1 = *(const float4*)(cb + rA * 256 + (((c0 + 1) ^ rx) << 4));
            short8 a = cvt2(a0, a1);
            int ch = ks * 4 + quad;
            int sl = (ch ^ rx) << 4;
            #pragma unroll
            for (int nt = 0; nt < 4; nt++) {
                const char* rowD = cb + 16384 + (nt * 16 + laneLo) * 128;
                short8 bD = *(const short8*)(rowD + sl);
                short8 bM = *(const short8*)(rowD + 64 * 128 + sl);
                accD[nt] = __builtin_amdgcn_mfma_f32_16x16x32_bf16(a, bD, accD[nt], 0, 0, 0);
                accM[nt] = __builtin_amdgcn_mfma_f32_16x16x32_bf16(a, bM, accM[nt], 0, 0, 0);
            }
        }
        __syncthreads();
    }

    float wa1[4], wa2[4];
    #pragma unroll
    for (int nt = 0; nt < 4; nt++) {
        wa1[nt] = Wa[nt * 16 + laneLo];
        wa2[nt] = Wa[F_ATTN + nt * 16 + laneLo];
    }

    // C/D layout: col = lane&15 (feature), row = quad*4 + reg (node)
    #pragma unroll
    for (int reg = 0; reg < 4; reg++) {
        int node = nodeBase + w * 16 + quad * 4 + reg;
        bool ok = node < N_NODES;
        int isD = ok ? (node_type[node] == 1) : 0;
        float p1 = 0.f, p2 = 0.f;
        #pragma unroll
        for (int nt = 0; nt < 4; nt++) {
            float v = isD ? accD[nt][reg] : accM[nt][reg];
            if (ok) z[(size_t)node * F_ATTN + nt * 16 + laneLo] = __float2bfloat16(v);
            p1 += v * wa1[nt];
            p2 += v * wa2[nt];
        }
        #pragma unroll
        for (int off = 8; off; off >>= 1) {
            p1 += __shfl_xor(p1, off);
            p2 += __shfl_xor(p2, off);
        }
        if (ok && laneLo == 0) { s1[node] = p1; s2[node] = p2; }
    }
}

// ---------------- Aggregation: one block per bin (128 nodes, 16 waves).
// Distribute bin edges to per-node LDS lists via LDS atomics, then wave w
// aggregates nodes w*8..w*8+7 with the 16-lane x 4-feature gather pattern.
// Gather loop runs in 4-edge granules (avg cnt ~ 20 -> few pad gathers).
// Weight recomputed: exp(leaky(s1[src]+s2[node])); softmax ratio identical
// without the max shift (logits O(1), no overflow).
__global__ __launch_bounds__(1024) void agg_kernel(
    const int* __restrict__ gcount, const int* __restrict__ bins,
    const float* __restrict__ s1, const float* __restrict__ s2,
    const __hip_bfloat16* __restrict__ z, float* __restrict__ out)
{
    __shared__ unsigned short list[128 * CAP];   // 16 KB
    __shared__ int lcnt[128];
    __shared__ float sW[16 * 64];                // 4 KB
    __shared__ int   sS[16 * 64];                // 4 KB
    int tid = threadIdx.x;
    int b   = blockIdx.x;
    if (tid < 128) lcnt[tid] = 0;
    __syncthreads();

    int bc = gcount[b]; if (bc > BINCAP) bc = BINCAP;
    for (int i = tid; i < bc; i += 1024) {
        int v = bins[(b << 12) + i];
        int n = v & 127;
        int s = v >> 7;
        int r = atomicAdd(&lcnt[n], 1);
        if (r < CAP) list[(n << 6) + r] = (unsigned short)s;
    }
    __syncthreads();

    int wv    = tid >> 6;            // 0..15
    int lane  = tid & 63;
    int fgrp  = (lane & 15) * 4;     // this lane's 4 features
    int ep    = lane >> 4;           // edge-slot offset 0..3
    int wbase = wv * 64;

    for (int j8 = 0; j8 < 8; j8++) {
        int ln   = wv * 8 + j8;                  // local node 0..127
        int node = (b << 7) + ln;
        bool nvalid = node < N_NODES;
        int cnt = nvalid ? lcnt[ln] : 0;
        if (cnt > CAP) cnt = CAP;                // overflow clamp

        int   src = 0;
        float wgt = 0.f;                         // pad slots keep w=0
        if (lane < cnt) {
            src = list[(ln << 6) + lane];
            float t = s1[src] + s2[node];
            float ev = (t > 0.f) ? t : SLOPE * t;
            wgt = __expf(ev);
        }
        float l = wgt;
        sW[wbase + lane] = wgt;                  // wave-private: no barrier
        sS[wbase + lane] = src;

        float4 h = {0.f, 0.f, 0.f, 0.f};
        int usteps = (cnt + 3) >> 2;             // 4-edge granules
        for (int uu = 0; uu < usteps; uu++) {    // pad slots (<=3) have w=0
            int slot = wbase + (uu << 2) + ep;
            float wj = sW[slot];
            int   sj = sS[slot];
            ushort4 zz = *(const ushort4*)((const unsigned short*)z +
                                           (size_t)sj * F_ATTN + fgrp);
            h.x += wj * bfu2f(zz.x);
            h.y += wj * bfu2f(zz.y);
            h.z += wj * bfu2f(zz.z);
            h.w += wj * bfu2f(zz.w);
        }
        // combine the 4 edge-slot groups (lanes differing in bits 4,5)
        #pragma unroll
        for (int off = 16; off <= 32; off <<= 1) {
            h.x += __shfl_xor(h.x, off);
            h.y += __shfl_xor(h.y, off);
            h.z += __shfl_xor(h.z, off);
            h.w += __shfl_xor(h.w, off);
        }
        #pragma unroll
        for (int off = 32; off; off >>= 1) l += __shfl_xor(l, off);

        if (ep == 0 && nvalid) {
            float inv = (cnt > 0) ? 1.f / l : 0.f;
            float4 o;
            float v;
            v = h.x * inv; o.x = (v > 0.f) ? v : (__expf(v) - 1.f);
            v = h.y * inv; o.y = (v > 0.f) ? v : (__expf(v) - 1.f);
            v = h.z * inv; o.z = (v > 0.f) ? v : (__expf(v) - 1.f);
            v = h.w * inv; o.w = (v > 0.f) ? v : (__expf(v) - 1.f);
            *(float4*)(out + (size_t)node * F_ATTN + fgrp) = o;
        }
    }
}

extern "C" void kernel_launch(void* const* d_in, const int* in_sizes, int n_in,
                              void* d_out, int out_size, void* d_ws, size_t ws_size,
                              hipStream_t stream) {
    const float* d_sim = (const float*)d_in[0];
    const float* m_sim = (const float*)d_in[1];
    const float* Wd    = (const float*)d_in[2];
    const float* Wm    = (const float*)d_in[3];
    const float* Wa    = (const float*)d_in[4];
    const int* node_type = (const int*)d_in[5];
    const int* edge_src  = (const int*)d_in[6];
    const int* edge_dst  = (const int*)d_in[7];
    float* out = (float*)d_out;

    char* ws = (char*)d_ws;
    // ws layout (bytes):
    __hip_bfloat16* z  = (__hip_bfloat16*)(ws + 0);        //  6,400,000
    float* s1          = (float*)(ws + 6400000);           //    200,000
    float* s2          = (float*)(ws + 6600000);           //    200,000
    int*   gcount      = (int*)  (ws + 6800000);           //      1,564
    short* Wb          = (short*)(ws + 7000000);           //    131,072 (16B aligned)
    int*   bins        = (int*)  (ws + 8388608);           //  6,406,144 (16KB-aligned bins)

    wcvt_kernel<<<(2 * F_ATTN * D_FEAT) / 256, 256, 0, stream>>>(Wd, Wm, Wb, gcount);
    fused_kernel<<<NB_TOT, 256, 0, stream>>>(
        d_sim, m_sim, Wb, Wa, node_type, edge_src, edge_dst,
        z, s1, s2, gcount, bins);
    agg_kernel<<<BINS, 1024, 0, stream>>>(gcount, bins, s1, s2, z, out);
}